// Round 11
// baseline (673.389 us; speedup 1.0000x reference)
//
#include <hip/hip_runtime.h>
#include <hip/hip_bf16.h>

#define N_NODES  50000
#define N_EDGES  800000
#define ND       64
#define ED       32
#define MSGD     128
#define HIDD     256
#define N_AGENTS 25000
#define EPAD     800064   // N_EDGES + 64 (tile padding)

typedef _Float16 f16;
typedef __attribute__((ext_vector_type(4))) _Float16 f16x4;
typedef __attribute__((ext_vector_type(8))) _Float16 f16x8;
typedef __attribute__((ext_vector_type(4))) float f32x4;
typedef unsigned short u16;
typedef unsigned int   u32;
typedef unsigned long long u64;

// ============================================================================
// pack all four weight matrices into fp16 MFMA A-fragment order.
// frag for 16x16x32: lane l, elem j <-> W[k = ks*32 + (l>>4)*8 + j][n = nt*16 + (l&15)]
// ============================================================================
__global__ __launch_bounds__(256) void pack_weights(
    const float* __restrict__ W1, const float* __restrict__ W2,
    const float* __restrict__ Wh1, const float* __restrict__ Wh2,
    f16* __restrict__ F1, f16* __restrict__ F2,
    f16* __restrict__ F3, f16* __restrict__ F4)
{
    int tid  = blockIdx.x * 256 + threadIdx.x;
    int grp  = tid >> 6, lane = tid & 63;
    const float* W; f16* D; int NT, stride, gl;
    if      (grp < 80)  { W = W1;  D = F1; NT = 16; stride = 256; gl = grp; }
    else if (grp < 144) { W = W2;  D = F2; NT = 8;  stride = 128; gl = grp - 80; }
    else if (grp < 208) { W = Wh1; D = F3; NT = 16; stride = 256; gl = grp - 144; }
    else if (grp < 336) { W = Wh2; D = F4; NT = 16; stride = 256; gl = grp - 208; }
    else return;
    int ks = gl / NT, nt = gl - ks * NT;
    int n  = nt * 16 + (lane & 15);
    int k0 = ks * 32 + (lane >> 4) * 8;
    f16* dst = D + ((size_t)gl * 64 + lane) * 8;
    #pragma unroll
    for (int j = 0; j < 8; ++j)
        dst[j] = (f16)W[(size_t)(k0 + j) * stride + n];
}

// ============================================================================
// compact: keep edges with recv < N_AGENTS; per-receiver rank via atomicAdd.
// ============================================================================
__global__ __launch_bounds__(256) void compact_kernel(
    const int* __restrict__ recv, int* __restrict__ elist,
    int* __restrict__ rlist, int* __restrict__ rankl,
    int* __restrict__ deg, int* __restrict__ cnt)
{
    int i = blockIdx.x * 256 + threadIdx.x;
    int r = recv[i];
    bool keep = (r < N_AGENTS);
    u64 m = __ballot(keep);
    int lane = threadIdx.x & 63;
    int tot = __popcll(m);
    int base = 0;
    if (lane == 0 && tot > 0) base = atomicAdd(cnt, tot);
    base = __shfl(base, 0, 64);
    if (keep) {
        int p = base + __popcll(m & ((1ull << lane) - 1ull));
        int rank = atomicAdd(&deg[r], 1);
        elist[p] = i;
        rlist[p] = r;
        rankl[p] = rank;
    }
}

// ============================================================================
// prefix: exclusive scan deg -> off[25001] (single block)
// ============================================================================
__global__ __launch_bounds__(1024) void prefix_kernel(
    const int* __restrict__ deg, int* __restrict__ off)
{
    __shared__ int part[1024];
    int t = threadIdx.x;
    int i0 = t * 25;
    int s = 0;
    #pragma unroll 1
    for (int i = 0; i < 25; ++i) {
        int idx = i0 + i;
        if (idx < N_AGENTS) s += deg[idx];
    }
    part[t] = s;
    __syncthreads();
    for (int d = 1; d < 1024; d <<= 1) {
        int v = (t >= d) ? part[t - d] : 0;
        __syncthreads();
        part[t] += v;
        __syncthreads();
    }
    int run = (t == 0) ? 0 : part[t - 1];
    #pragma unroll 1
    for (int i = 0; i < 25; ++i) {
        int idx = i0 + i;
        if (idx < N_AGENTS) {
            off[idx] = run;
            run += deg[idx];
        }
    }
    if (t == 1023) off[N_AGENTS] = part[1023];
}

// ============================================================================
// scatter (no atomics): position = off[r] + rank
// ============================================================================
__global__ __launch_bounds__(256) void scatter_kernel(
    const int* __restrict__ elist, const int* __restrict__ rlist,
    const int* __restrict__ rankl, const int* __restrict__ off,
    const int* __restrict__ cnt, int* __restrict__ eidb)
{
    int n = cnt[0];
    for (int ci = blockIdx.x * 256 + threadIdx.x; ci < n; ci += gridDim.x * 256) {
        eidb[off[rlist[ci]] + rankl[ci]] = elist[ci];
    }
}

// ============================================================================
// Edge MLP + FUSED softmax-aggregation.  R4-proven staging idiom (DO NOT
// restructure: R8/R9 variants blow FETCH 120->450+ MB).  M=32 tiles, 512 thr,
// grid 1024.  After layer-2, tile-local segmented reduction over the (sorted)
// receiver segments flushes e*msg partials into aggr[] via fp32 atomics;
// denom[] accumulated per edge.  msg/evals global arrays are GONE (-204 MB).
// ============================================================================
__global__ __launch_bounds__(512, 4) void edge_mlp_mfma(
    const float* __restrict__ nf, const float* __restrict__ ef,
    const f16* __restrict__ F1, const f16* __restrict__ F2,
    const float* __restrict__ b1, const float* __restrict__ b2,
    const float* __restrict__ wg, const float* __restrict__ bg,
    const int* __restrict__ send, const int* __restrict__ recv,
    const int* __restrict__ eidb, const int* __restrict__ cnt,
    float* __restrict__ aggr, float* __restrict__ denom)
{
    __shared__ __align__(16) f16 XF[10][64][8];    // 10 KB
    __shared__ __align__(16) f16 HB[16][64][8];    // 16 KB
    __shared__ __align__(16) f16 msgt[32][136];    // 8.5 KB
    __shared__ float lpart[8][32];
    __shared__ float evs[32];
    __shared__ int   rsegS[32];

    const int tid  = threadIdx.x;
    const int wv   = tid >> 6;
    const int lane = tid & 63;
    const int q    = lane >> 4;
    const int li   = lane & 15;
    const int cntv   = cnt[0];
    const int ntiles = (cntv + 31) >> 5;
    const int G      = gridDim.x;

    // stationary weight fragments: W1 2 col-tiles + W2 1 col-tile per wave
    f16x8 w1[2][5], w2[8];
    #pragma unroll
    for (int ntl = 0; ntl < 2; ++ntl)
        #pragma unroll
        for (int ks = 0; ks < 5; ++ks)
            w1[ntl][ks] = *(const f16x8*)(F1 + (((size_t)(ks * 16 + 2 * wv + ntl)) * 64 + lane) * 8);
    #pragma unroll
    for (int ks = 0; ks < 8; ++ks)
        w2[ks] = *(const f16x8*)(F2 + (((size_t)(ks * 8 + wv)) * 64 + lane) * 8);

    const float4 ba  = *(const float4*)&b1[wv * 32 + q * 4];
    const float4 bb  = *(const float4*)&b1[wv * 32 + 16 + q * 4];
    const float4 bc  = *(const float4*)&b2[wv * 16 + q * 4];
    const float4 wg4 = *(const float4*)&wg[wv * 16 + q * 4];
    const float  bgv = bg[0];

    for (int t = blockIdx.x; t < ntiles; t += G) {
        const int e0 = t * 32;

        // ---- stage x = [nf[s]|nf[r]|ef] -> fp16 B-frag order (R4 idiom) ----
        for (int idx = tid; idx < 1280; idx += 512) {
            int e = idx / 40, g = idx - e * 40;
            int eid = eidb[e0 + e];
            float4 v;
            if (g < 16)      v = ((const float4*)nf)[(size_t)send[eid] * 16 + g];
            else if (g < 32) {
                int r = recv[eid];
                if (g == 16) rsegS[e] = r;        // free: r already loaded
                v = ((const float4*)nf)[(size_t)r * 16 + (g - 16)];
            }
            else             v = ((const float4*)ef)[(size_t)eid * 8 + (g - 32)];
            int k0   = g * 4;
            int slot = (e >> 4) * 5 + (k0 >> 5);
            int ln   = (e & 15) + 16 * ((k0 & 31) >> 3);
            int j0   = k0 & 7;
            f16x4 h;
            h.x = (f16)v.x; h.y = (f16)v.y; h.z = (f16)v.z; h.w = (f16)v.w;
            *(f16x4*)&XF[slot][ln][j0] = h;
        }
        __syncthreads();                          // B1

        // ---- layer 1: h[col][edge] = W1^T x^T ----
        f32x4 acc[2][2];   // [eh][ntl]
        acc[0][0] = f32x4{ba.x, ba.y, ba.z, ba.w}; acc[1][0] = acc[0][0];
        acc[0][1] = f32x4{bb.x, bb.y, bb.z, bb.w}; acc[1][1] = acc[0][1];
        #pragma unroll
        for (int ks = 0; ks < 5; ++ks)
            #pragma unroll
            for (int eh = 0; eh < 2; ++eh) {
                f16x8 xh = *(const f16x8*)XF[eh * 5 + ks][lane];
                acc[eh][0] = __builtin_amdgcn_mfma_f32_16x16x32_f16(w1[0][ks], xh, acc[eh][0], 0, 0, 0);
                acc[eh][1] = __builtin_amdgcn_mfma_f32_16x16x32_f16(w1[1][ks], xh, acc[eh][1], 0, 0, 0);
            }
        #pragma unroll
        for (int eh = 0; eh < 2; ++eh)
            #pragma unroll
            for (int ntl = 0; ntl < 2; ++ntl) {
                f16x4 hv;
                hv.x = (f16)fmaxf(acc[eh][ntl][0], 0.f);
                hv.y = (f16)fmaxf(acc[eh][ntl][1], 0.f);
                hv.z = (f16)fmaxf(acc[eh][ntl][2], 0.f);
                hv.w = (f16)fmaxf(acc[eh][ntl][3], 0.f);
                int l2 = li + 16 * (2 * ntl + (q >> 1));
                int j0 = (q & 1) * 4;
                *(f16x4*)&HB[eh * 8 + wv][l2][j0] = hv;
            }
        __syncthreads();                          // B2

        // ---- layer 2: msg[col][edge] = W2^T h^T + gate partial ----
        f32x4 acc2[2];
        acc2[0] = f32x4{bc.x, bc.y, bc.z, bc.w}; acc2[1] = acc2[0];
        #pragma unroll
        for (int ks2 = 0; ks2 < 8; ++ks2)
            #pragma unroll
            for (int eh = 0; eh < 2; ++eh) {
                f16x8 hh = *(const f16x8*)HB[eh * 8 + ks2][lane];
                acc2[eh] = __builtin_amdgcn_mfma_f32_16x16x32_f16(w2[ks2], hh, acc2[eh], 0, 0, 0);
            }
        {
            float pr[2];
            #pragma unroll
            for (int eh = 0; eh < 2; ++eh) {
                float v0 = fmaxf(acc2[eh][0], 0.f);
                float v1 = fmaxf(acc2[eh][1], 0.f);
                float v2 = fmaxf(acc2[eh][2], 0.f);
                float v3 = fmaxf(acc2[eh][3], 0.f);
                f16x4 mm;
                mm.x = (f16)v0; mm.y = (f16)v1; mm.z = (f16)v2; mm.w = (f16)v3;
                *(f16x4*)&msgt[eh * 16 + li][wv * 16 + q * 4] = mm;
                float p = v0 * wg4.x + v1 * wg4.y + v2 * wg4.z + v3 * wg4.w;
                p += __shfl_xor(p, 16, 64);
                p += __shfl_xor(p, 32, 64);
                pr[eh] = p;
            }
            if (lane < 16) {
                lpart[wv][li]      = pr[0];
                lpart[wv][16 + li] = pr[1];
            }
        }
        __syncthreads();                          // B3: msgt + lpart ready

        // ---- evs = exp(logit) (0 for padded edges) + denom atomics ----
        if (tid < 32) {
            float s2 = bgv;
            #pragma unroll
            for (int w = 0; w < 8; ++w) s2 += lpart[w][tid];
            bool valid = (e0 + tid < cntv);
            float e = valid ? expf(s2) : 0.0f;    // softmax shift-invariant
            evs[tid] = e;
            if (valid) atomicAdd(&denom[rsegS[tid]], e);
        }
        __syncthreads();                          // B4: evs ready

        // ---- tile-local segmented reduce: aggr[r][c] += sum e_k*msg[k][c] ----
        {
            int base = (tid >> 7) * 8;            // 4 quarters x 8 edges
            int c    = tid & 127;
            float a  = 0.f;
            #pragma unroll
            for (int k = base; k < base + 8; ++k) {
                a = fmaf(evs[k], (float)msgt[k][c], a);
                bool fl = (k == base + 7) || (rsegS[k + 1] != rsegS[k]);
                if (fl) {
                    if (a != 0.f)
                        atomicAdd(&aggr[(size_t)rsegS[k] * MSGD + c], a);
                    a = 0.f;
                }
            }
        }
        // next iteration's B1 protects msgt/evs/rsegS reuse
    }
}

// ============================================================================
// Agent MLP: normalize aggr/denom -> fp16 frags -> 2-layer MFMA MLP -> tanh.
// 1024 thr, 32 agents/block.
// ============================================================================
__global__ __launch_bounds__(1024, 4) void agent_mlp_mfma(
    const float* __restrict__ aggr, const float* __restrict__ denom,
    const f16* __restrict__ F3, const f16* __restrict__ F4,
    const float* __restrict__ bh1, const float* __restrict__ bh2,
    const float* __restrict__ Wout, const float* __restrict__ bout,
    float* __restrict__ out)
{
    __shared__ __align__(16) f16 XA[8][64][8];     // 8 KB
    __shared__ __align__(16) f16 HB2[16][64][8];   // 16 KB
    __shared__ float lpart[16][32];

    const int tid  = threadIdx.x;
    const int wv   = tid >> 6;
    const int lane = tid & 63;
    const int q    = lane >> 4;
    const int li   = lane & 15;
    const int a0i  = blockIdx.x * 32;

    // ---- normalize straight into XA fragment layout ----
    {
        int g = tid >> 5, c = tid & 31;   // agent a0i+g, cols [c*4, c*4+4)
        int r = a0i + g;
        float4 v = make_float4(0.f, 0.f, 0.f, 0.f);
        float inv = 0.f;
        if (r < N_AGENTS) {
            v = ((const float4*)aggr)[(size_t)r * 32 + c];
            inv = 1.0f / (denom[r] + 1e-9f);
        }
        int k0   = c * 4;
        int slot = (g >> 4) * 4 + (k0 >> 5);
        int ln   = (g & 15) + 16 * ((k0 & 31) >> 3);
        int j0   = k0 & 7;
        f16x4 h;
        h.x = (f16)(v.x * inv); h.y = (f16)(v.y * inv);
        h.z = (f16)(v.z * inv); h.w = (f16)(v.w * inv);
        *(f16x4*)&XA[slot][ln][j0] = h;
    }
    __syncthreads();

    // ---- weight fragments + layer 1 ----
    f16x8 wh1[4], wh2[8];
    #pragma unroll
    for (int ks = 0; ks < 4; ++ks)
        wh1[ks] = *(const f16x8*)(F3 + (((size_t)(ks * 16 + wv)) * 64 + lane) * 8);
    #pragma unroll
    for (int ks = 0; ks < 8; ++ks)
        wh2[ks] = *(const f16x8*)(F4 + (((size_t)(ks * 16 + wv)) * 64 + lane) * 8);

    f32x4 acc[2] = {};
    #pragma unroll
    for (int ks = 0; ks < 4; ++ks)
        #pragma unroll
        for (int eh = 0; eh < 2; ++eh) {
            f16x8 xh = *(const f16x8*)XA[eh * 4 + ks][lane];
            acc[eh] = __builtin_amdgcn_mfma_f32_16x16x32_f16(wh1[ks], xh, acc[eh], 0, 0, 0);
        }
    {
        const float4 b1v = ((const float4*)bh1)[wv * 4 + q];
        #pragma unroll
        for (int eh = 0; eh < 2; ++eh) {
            f16x4 hv;
            hv.x = (f16)fmaxf(acc[eh][0] + b1v.x, 0.f);
            hv.y = (f16)fmaxf(acc[eh][1] + b1v.y, 0.f);
            hv.z = (f16)fmaxf(acc[eh][2] + b1v.z, 0.f);
            hv.w = (f16)fmaxf(acc[eh][3] + b1v.w, 0.f);
            int l2 = li + 16 * ((wv & 1) * 2 + (q >> 1));
            int j0 = (q & 1) * 4;
            *(f16x4*)&HB2[eh * 8 + (wv >> 1)][l2][j0] = hv;
        }
    }
    __syncthreads();

    // ---- layer 2 + output partial ----
    f32x4 acc2[2] = {};
    #pragma unroll
    for (int ks2 = 0; ks2 < 8; ++ks2)
        #pragma unroll
        for (int eh = 0; eh < 2; ++eh) {
            f16x8 hh = *(const f16x8*)HB2[eh * 8 + ks2][lane];
            acc2[eh] = __builtin_amdgcn_mfma_f32_16x16x32_f16(wh2[ks2], hh, acc2[eh], 0, 0, 0);
        }
    {
        const float4 b2v = ((const float4*)bh2)[wv * 4 + q];
        const float4 wo4 = ((const float4*)Wout)[wv * 4 + q];
        float pr[2];
        #pragma unroll
        for (int eh = 0; eh < 2; ++eh) {
            float p = fmaxf(acc2[eh][0] + b2v.x, 0.f) * wo4.x
                    + fmaxf(acc2[eh][1] + b2v.y, 0.f) * wo4.y
                    + fmaxf(acc2[eh][2] + b2v.z, 0.f) * wo4.z
                    + fmaxf(acc2[eh][3] + b2v.w, 0.f) * wo4.w;
            p += __shfl_xor(p, 16, 64);
            p += __shfl_xor(p, 32, 64);
            pr[eh] = p;
        }
        if (lane < 16) {
            lpart[wv][li]      = pr[0];
            lpart[wv][16 + li] = pr[1];
        }
    }
    __syncthreads();

    if (tid < 32 && a0i + tid < N_AGENTS) {
        float s = bout[0];
        #pragma unroll
        for (int w = 0; w < 16; ++w) s += lpart[w][tid];
        out[a0i + tid] = tanhf(s);
    }
}

// ============================================================================
extern "C" void kernel_launch(void* const* d_in, const int* in_sizes, int n_in,
                              void* d_out, int out_size, void* d_ws, size_t ws_size,
                              hipStream_t stream)
{
    const float* nf   = (const float*)d_in[0];
    const float* ef   = (const float*)d_in[1];
    const float* W1   = (const float*)d_in[2];
    const float* b1   = (const float*)d_in[3];
    const float* W2   = (const float*)d_in[4];
    const float* b2   = (const float*)d_in[5];
    const float* wg   = (const float*)d_in[6];
    const float* bg   = (const float*)d_in[7];
    const float* Wh1  = (const float*)d_in[8];
    const float* bh1  = (const float*)d_in[9];
    const float* Wh2  = (const float*)d_in[10];
    const float* bh2  = (const float*)d_in[11];
    const float* Wout = (const float*)d_in[12];
    const float* bout = (const float*)d_in[13];
    const int*   send = (const int*)d_in[14];
    const int*   recv = (const int*)d_in[15];

    // workspace: [cnt|deg|denom|eidb|aggr] zeroed, then the rest (~27 MB total)
    char* ws = (char*)d_ws;
    int*   cntp  = (int*)ws;           ws += 16;
    int*   deg   = (int*)ws;           ws += (size_t)N_AGENTS * 4;
    float* denom = (float*)ws;         ws += (size_t)N_AGENTS * 4;
    int*   eidb  = (int*)ws;           ws += (size_t)EPAD * 4;
    float* aggr  = (float*)ws;         ws += (size_t)N_AGENTS * MSGD * 4;
    size_t zero_bytes = (size_t)(ws - (char*)d_ws);
    int*   elist = (int*)ws;           ws += (size_t)EPAD * 4;
    int*   rlist = (int*)ws;           ws += (size_t)EPAD * 4;
    int*   rankl = (int*)ws;           ws += (size_t)EPAD * 4;
    int*   off   = (int*)ws;           ws += (size_t)(N_AGENTS + 8) * 4;
    f16*   F1    = (f16*)ws;           ws += (size_t)160 * 256 * 2;
    f16*   F2    = (f16*)ws;           ws += (size_t)256 * 128 * 2;
    f16*   F3    = (f16*)ws;           ws += (size_t)128 * 256 * 2;
    f16*   F4    = (f16*)ws;           ws += (size_t)256 * 256 * 2;

    hipMemsetAsync(d_ws, 0, zero_bytes, stream);

    pack_weights<<<84, 256, 0, stream>>>(W1, W2, Wh1, Wh2, F1, F2, F3, F4);
    compact_kernel<<<N_EDGES / 256, 256, 0, stream>>>(
        recv, elist, rlist, rankl, deg, cntp);
    prefix_kernel<<<1, 1024, 0, stream>>>(deg, off);
    scatter_kernel<<<1024, 256, 0, stream>>>(elist, rlist, rankl, off, cntp, eidb);
    edge_mlp_mfma<<<1024, 512, 0, stream>>>(
        nf, ef, F1, F2, b1, b2, wg, bg, send, recv, eidb, cntp, aggr, denom);
    agent_mlp_mfma<<<(N_AGENTS + 31) / 32, 1024, 0, stream>>>(
        aggr, denom, F3, F4, bh1, bh2, Wout, bout, (float*)d_out);
}

// Round 12
// 627.612 us; speedup vs baseline: 1.0729x; 1.0729x over previous
//
#include <hip/hip_runtime.h>
#include <hip/hip_bf16.h>

#define N_NODES  50000
#define N_EDGES  800000
#define ND       64
#define ED       32
#define MSGD     128
#define HIDD     256
#define N_AGENTS 25000
#define EPAD     800064   // N_EDGES + 64 (tile padding)

typedef _Float16 f16;
typedef __attribute__((ext_vector_type(4))) _Float16 f16x4;
typedef __attribute__((ext_vector_type(8))) _Float16 f16x8;
typedef __attribute__((ext_vector_type(4))) float f32x4;
typedef unsigned short u16;
typedef unsigned int   u32;
typedef unsigned long long u64;

// ============================================================================
// pack all four weight matrices into fp16 MFMA A-fragment order.
// frag for 16x16x32: lane l, elem j <-> W[k = ks*32 + (l>>4)*8 + j][n = nt*16 + (l&15)]
// ============================================================================
__global__ __launch_bounds__(256) void pack_weights(
    const float* __restrict__ W1, const float* __restrict__ W2,
    const float* __restrict__ Wh1, const float* __restrict__ Wh2,
    f16* __restrict__ F1, f16* __restrict__ F2,
    f16* __restrict__ F3, f16* __restrict__ F4)
{
    int tid  = blockIdx.x * 256 + threadIdx.x;
    int grp  = tid >> 6, lane = tid & 63;
    const float* W; f16* D; int NT, stride, gl;
    if      (grp < 80)  { W = W1;  D = F1; NT = 16; stride = 256; gl = grp; }
    else if (grp < 144) { W = W2;  D = F2; NT = 8;  stride = 128; gl = grp - 80; }
    else if (grp < 208) { W = Wh1; D = F3; NT = 16; stride = 256; gl = grp - 144; }
    else if (grp < 336) { W = Wh2; D = F4; NT = 16; stride = 256; gl = grp - 208; }
    else return;
    int ks = gl / NT, nt = gl - ks * NT;
    int n  = nt * 16 + (lane & 15);
    int k0 = ks * 32 + (lane >> 4) * 8;
    f16* dst = D + ((size_t)gl * 64 + lane) * 8;
    #pragma unroll
    for (int j = 0; j < 8; ++j)
        dst[j] = (f16)W[(size_t)(k0 + j) * stride + n];
}

// ============================================================================
// compact: keep edges with recv < N_AGENTS; per-receiver rank via atomicAdd.
// ============================================================================
__global__ __launch_bounds__(256) void compact_kernel(
    const int* __restrict__ recv, int* __restrict__ elist,
    int* __restrict__ rlist, int* __restrict__ rankl,
    int* __restrict__ deg, int* __restrict__ cnt)
{
    int i = blockIdx.x * 256 + threadIdx.x;
    int r = recv[i];
    bool keep = (r < N_AGENTS);
    u64 m = __ballot(keep);
    int lane = threadIdx.x & 63;
    int tot = __popcll(m);
    int base = 0;
    if (lane == 0 && tot > 0) base = atomicAdd(cnt, tot);
    base = __shfl(base, 0, 64);
    if (keep) {
        int p = base + __popcll(m & ((1ull << lane) - 1ull));
        int rank = atomicAdd(&deg[r], 1);
        elist[p] = i;
        rlist[p] = r;
        rankl[p] = rank;
    }
}

// ============================================================================
// prefix: exclusive scan deg -> off[25001] (single block)
// ============================================================================
__global__ __launch_bounds__(1024) void prefix_kernel(
    const int* __restrict__ deg, int* __restrict__ off)
{
    __shared__ int part[1024];
    int t = threadIdx.x;
    int i0 = t * 25;
    int s = 0;
    #pragma unroll 1
    for (int i = 0; i < 25; ++i) {
        int idx = i0 + i;
        if (idx < N_AGENTS) s += deg[idx];
    }
    part[t] = s;
    __syncthreads();
    for (int d = 1; d < 1024; d <<= 1) {
        int v = (t >= d) ? part[t - d] : 0;
        __syncthreads();
        part[t] += v;
        __syncthreads();
    }
    int run = (t == 0) ? 0 : part[t - 1];
    #pragma unroll 1
    for (int i = 0; i < 25; ++i) {
        int idx = i0 + i;
        if (idx < N_AGENTS) {
            off[idx] = run;
            run += deg[idx];
        }
    }
    if (t == 1023) off[N_AGENTS] = part[1023];
}

// ============================================================================
// scatter (no atomics): position = off[r] + rank
// ============================================================================
__global__ __launch_bounds__(256) void scatter_kernel(
    const int* __restrict__ elist, const int* __restrict__ rlist,
    const int* __restrict__ rankl, const int* __restrict__ off,
    const int* __restrict__ cnt, int* __restrict__ eidb)
{
    int n = cnt[0];
    for (int ci = blockIdx.x * 256 + threadIdx.x; ci < n; ci += gridDim.x * 256) {
        eidb[off[rlist[ci]] + rankl[ci]] = elist[ci];
    }
}

// ============================================================================
// Edge MLP — R4/R10 structure (measured optimum: FETCH ~120 MB).  fp16 MFMA,
// weight-stationary, bucket-ordered, M=32 tiles, 512 thr = 8 waves, 3
// barriers/tile, direct-eid staging idiom (do not restructure: R8/R9 variants
// blow FETCH to 450-514 MB; R11 fused-agg epilogue +122 us).
// R12 delta: grid 512 -> 1024 (2 -> 4 blocks/CU; grid was the occupancy cap).
// ============================================================================
__global__ __launch_bounds__(512, 4) void edge_mlp_mfma(
    const float* __restrict__ nf, const float* __restrict__ ef,
    const f16* __restrict__ F1, const f16* __restrict__ F2,
    const float* __restrict__ b1, const float* __restrict__ b2,
    const float* __restrict__ wg, const float* __restrict__ bg,
    const int* __restrict__ send, const int* __restrict__ recv,
    const int* __restrict__ eidb, const int* __restrict__ cnt,
    f16* __restrict__ msg_out, float* __restrict__ evals)
{
    __shared__ __align__(16) f16 XF[10][64][8];    // 10 KB
    __shared__ __align__(16) f16 HB[16][64][8];    // 16 KB
    __shared__ __align__(16) f16 msgt[32][136];    // 8.5 KB
    __shared__ float lpart[8][32];

    const int tid  = threadIdx.x;
    const int wv   = tid >> 6;
    const int lane = tid & 63;
    const int q    = lane >> 4;
    const int li   = lane & 15;
    const int cntv   = cnt[0];
    const int ntiles = (cntv + 31) >> 5;
    const int G      = gridDim.x;

    // stationary weight fragments: W1 2 col-tiles + W2 1 col-tile per wave
    f16x8 w1[2][5], w2[8];
    #pragma unroll
    for (int ntl = 0; ntl < 2; ++ntl)
        #pragma unroll
        for (int ks = 0; ks < 5; ++ks)
            w1[ntl][ks] = *(const f16x8*)(F1 + (((size_t)(ks * 16 + 2 * wv + ntl)) * 64 + lane) * 8);
    #pragma unroll
    for (int ks = 0; ks < 8; ++ks)
        w2[ks] = *(const f16x8*)(F2 + (((size_t)(ks * 8 + wv)) * 64 + lane) * 8);

    const float4 ba  = *(const float4*)&b1[wv * 32 + q * 4];
    const float4 bb  = *(const float4*)&b1[wv * 32 + 16 + q * 4];
    const float4 bc  = *(const float4*)&b2[wv * 16 + q * 4];
    const float4 wg4 = *(const float4*)&wg[wv * 16 + q * 4];
    const float  bgv = bg[0];

    for (int t = blockIdx.x; t < ntiles; t += G) {
        const int e0 = t * 32;

        // ---- stage x = [nf[s]|nf[r]|ef] -> fp16 B-frag order ----
        for (int idx = tid; idx < 1280; idx += 512) {
            int e = idx / 40, g = idx - e * 40;
            int eid = eidb[e0 + e];
            float4 v;
            if (g < 16)      v = ((const float4*)nf)[(size_t)send[eid] * 16 + g];
            else if (g < 32) v = ((const float4*)nf)[(size_t)recv[eid] * 16 + (g - 16)];
            else             v = ((const float4*)ef)[(size_t)eid * 8 + (g - 32)];
            int k0   = g * 4;
            int slot = (e >> 4) * 5 + (k0 >> 5);
            int ln   = (e & 15) + 16 * ((k0 & 31) >> 3);
            int j0   = k0 & 7;
            f16x4 h;
            h.x = (f16)v.x; h.y = (f16)v.y; h.z = (f16)v.z; h.w = (f16)v.w;
            *(f16x4*)&XF[slot][ln][j0] = h;
        }
        __syncthreads();

        // ---- layer 1: h[col][edge] = W1^T x^T ----
        f32x4 acc[2][2];   // [eh][ntl]
        acc[0][0] = f32x4{ba.x, ba.y, ba.z, ba.w}; acc[1][0] = acc[0][0];
        acc[0][1] = f32x4{bb.x, bb.y, bb.z, bb.w}; acc[1][1] = acc[0][1];
        #pragma unroll
        for (int ks = 0; ks < 5; ++ks)
            #pragma unroll
            for (int eh = 0; eh < 2; ++eh) {
                f16x8 xh = *(const f16x8*)XF[eh * 5 + ks][lane];
                acc[eh][0] = __builtin_amdgcn_mfma_f32_16x16x32_f16(w1[0][ks], xh, acc[eh][0], 0, 0, 0);
                acc[eh][1] = __builtin_amdgcn_mfma_f32_16x16x32_f16(w1[1][ks], xh, acc[eh][1], 0, 0, 0);
            }
        // relu + stash h as layer-2 B frags
        #pragma unroll
        for (int eh = 0; eh < 2; ++eh)
            #pragma unroll
            for (int ntl = 0; ntl < 2; ++ntl) {
                f16x4 hv;
                hv.x = (f16)fmaxf(acc[eh][ntl][0], 0.f);
                hv.y = (f16)fmaxf(acc[eh][ntl][1], 0.f);
                hv.z = (f16)fmaxf(acc[eh][ntl][2], 0.f);
                hv.w = (f16)fmaxf(acc[eh][ntl][3], 0.f);
                int l2 = li + 16 * (2 * ntl + (q >> 1));
                int j0 = (q & 1) * 4;
                *(f16x4*)&HB[eh * 8 + wv][l2][j0] = hv;
            }
        __syncthreads();

        // ---- layer 2: msg[col][edge] = W2^T h^T ----
        f32x4 acc2[2];
        acc2[0] = f32x4{bc.x, bc.y, bc.z, bc.w}; acc2[1] = acc2[0];
        #pragma unroll
        for (int ks2 = 0; ks2 < 8; ++ks2)
            #pragma unroll
            for (int eh = 0; eh < 2; ++eh) {
                f16x8 hh = *(const f16x8*)HB[eh * 8 + ks2][lane];
                acc2[eh] = __builtin_amdgcn_mfma_f32_16x16x32_f16(w2[ks2], hh, acc2[eh], 0, 0, 0);
            }
        // relu + gate partial + msg stash
        {
            float pr[2];
            #pragma unroll
            for (int eh = 0; eh < 2; ++eh) {
                float v0 = fmaxf(acc2[eh][0], 0.f);
                float v1 = fmaxf(acc2[eh][1], 0.f);
                float v2 = fmaxf(acc2[eh][2], 0.f);
                float v3 = fmaxf(acc2[eh][3], 0.f);
                f16x4 mm;
                mm.x = (f16)v0; mm.y = (f16)v1; mm.z = (f16)v2; mm.w = (f16)v3;
                *(f16x4*)&msgt[eh * 16 + li][wv * 16 + q * 4] = mm;
                float p = v0 * wg4.x + v1 * wg4.y + v2 * wg4.z + v3 * wg4.w;
                p += __shfl_xor(p, 16, 64);
                p += __shfl_xor(p, 32, 64);
                pr[eh] = p;
            }
            if (lane < 16) {
                lpart[wv][li]      = pr[0];
                lpart[wv][16 + li] = pr[1];
            }
        }
        __syncthreads();

        // ---- writeback: coalesced msg rows + evals = exp(logit) ----
        {
            int row = tid >> 4, cg = tid & 15;
            *(uint4*)(msg_out + (size_t)(e0 + row) * 128 + cg * 8) =
                *(const uint4*)&msgt[row][cg * 8];
        }
        if (tid < 32) {
            float s2 = bgv;
            #pragma unroll
            for (int w = 0; w < 8; ++w) s2 += lpart[w][tid];
            evals[e0 + tid] = expf(s2);   // softmax shift-invariant; |logit|~O(5)
        }
    }
}

// ============================================================================
// Fused CSR softmax-aggregation + agent MLP. 1024 thr, 32 receivers/block.
// Aggregation: 32 threads per receiver, 4 cols each (8 B/lane), sequential
// bucket rows (zero atomics, no aggr round-trip). Then fp16-MFMA 2-layer MLP.
// ============================================================================
__global__ __launch_bounds__(1024, 4) void agg_agent_mfma(
    const int* __restrict__ off, const float* __restrict__ evals,
    const f16* __restrict__ msg,
    const f16* __restrict__ F3, const f16* __restrict__ F4,
    const float* __restrict__ bh1, const float* __restrict__ bh2,
    const float* __restrict__ Wout, const float* __restrict__ bout,
    float* __restrict__ out)
{
    __shared__ __align__(16) f16 XA[8][64][8];     // 8 KB
    __shared__ __align__(16) f16 HB2[16][64][8];   // 16 KB
    __shared__ float lpart[16][32];

    const int tid  = threadIdx.x;
    const int wv   = tid >> 6;
    const int lane = tid & 63;
    const int q    = lane >> 4;
    const int li   = lane & 15;
    const int a0i  = blockIdx.x * 32;

    // ---- aggregation straight into XA fragment layout ----
    {
        int g = tid >> 5, c = tid & 31;   // receiver a0i+g, cols [c*4, c*4+4)
        int r = a0i + g;
        float den = 1e-9f;
        float4 acc = make_float4(0.f, 0.f, 0.f, 0.f);
        if (r < N_AGENTS) {
            int beg = off[r], end = off[r + 1];
            const u64* mp = (const u64*)(msg + (size_t)beg * 128) + c;
            for (int p = beg; p < end; ++p, mp += 32) {
                float e = evals[p];
                den += e;
                union { u64 u; f16 h[4]; } cv; cv.u = *mp;
                acc.x = fmaf(e, (float)cv.h[0], acc.x);
                acc.y = fmaf(e, (float)cv.h[1], acc.y);
                acc.z = fmaf(e, (float)cv.h[2], acc.z);
                acc.w = fmaf(e, (float)cv.h[3], acc.w);
            }
        }
        float inv = 1.0f / den;
        int k0   = c * 4;
        int slot = (g >> 4) * 4 + (k0 >> 5);
        int ln   = (g & 15) + 16 * ((k0 & 31) >> 3);
        int j0   = k0 & 7;
        f16x4 h;
        h.x = (f16)(acc.x * inv); h.y = (f16)(acc.y * inv);
        h.z = (f16)(acc.z * inv); h.w = (f16)(acc.w * inv);
        *(f16x4*)&XA[slot][ln][j0] = h;
    }
    __syncthreads();

    // ---- weight fragments + layer 1 ----
    f16x8 wh1[4], wh2[8];
    #pragma unroll
    for (int ks = 0; ks < 4; ++ks)
        wh1[ks] = *(const f16x8*)(F3 + (((size_t)(ks * 16 + wv)) * 64 + lane) * 8);
    #pragma unroll
    for (int ks = 0; ks < 8; ++ks)
        wh2[ks] = *(const f16x8*)(F4 + (((size_t)(ks * 16 + wv)) * 64 + lane) * 8);

    f32x4 acc[2] = {};
    #pragma unroll
    for (int ks = 0; ks < 4; ++ks)
        #pragma unroll
        for (int eh = 0; eh < 2; ++eh) {
            f16x8 xh = *(const f16x8*)XA[eh * 4 + ks][lane];
            acc[eh] = __builtin_amdgcn_mfma_f32_16x16x32_f16(wh1[ks], xh, acc[eh], 0, 0, 0);
        }
    {
        const float4 b1v = ((const float4*)bh1)[wv * 4 + q];
        #pragma unroll
        for (int eh = 0; eh < 2; ++eh) {
            f16x4 hv;
            hv.x = (f16)fmaxf(acc[eh][0] + b1v.x, 0.f);
            hv.y = (f16)fmaxf(acc[eh][1] + b1v.y, 0.f);
            hv.z = (f16)fmaxf(acc[eh][2] + b1v.z, 0.f);
            hv.w = (f16)fmaxf(acc[eh][3] + b1v.w, 0.f);
            int l2 = li + 16 * ((wv & 1) * 2 + (q >> 1));
            int j0 = (q & 1) * 4;
            *(f16x4*)&HB2[eh * 8 + (wv >> 1)][l2][j0] = hv;
        }
    }
    __syncthreads();

    // ---- layer 2 + output partial ----
    f32x4 acc2[2] = {};
    #pragma unroll
    for (int ks2 = 0; ks2 < 8; ++ks2)
        #pragma unroll
        for (int eh = 0; eh < 2; ++eh) {
            f16x8 hh = *(const f16x8*)HB2[eh * 8 + ks2][lane];
            acc2[eh] = __builtin_amdgcn_mfma_f32_16x16x32_f16(wh2[ks2], hh, acc2[eh], 0, 0, 0);
        }
    {
        const float4 b2v = ((const float4*)bh2)[wv * 4 + q];
        const float4 wo4 = ((const float4*)Wout)[wv * 4 + q];
        float pr[2];
        #pragma unroll
        for (int eh = 0; eh < 2; ++eh) {
            float p = fmaxf(acc2[eh][0] + b2v.x, 0.f) * wo4.x
                    + fmaxf(acc2[eh][1] + b2v.y, 0.f) * wo4.y
                    + fmaxf(acc2[eh][2] + b2v.z, 0.f) * wo4.z
                    + fmaxf(acc2[eh][3] + b2v.w, 0.f) * wo4.w;
            p += __shfl_xor(p, 16, 64);
            p += __shfl_xor(p, 32, 64);
            pr[eh] = p;
        }
        if (lane < 16) {
            lpart[wv][li]      = pr[0];
            lpart[wv][16 + li] = pr[1];
        }
    }
    __syncthreads();

    if (tid < 32 && a0i + tid < N_AGENTS) {
        float s = bout[0];
        #pragma unroll
        for (int w = 0; w < 16; ++w) s += lpart[w][tid];
        out[a0i + tid] = tanhf(s);
    }
}

// ============================================================================
extern "C" void kernel_launch(void* const* d_in, const int* in_sizes, int n_in,
                              void* d_out, int out_size, void* d_ws, size_t ws_size,
                              hipStream_t stream)
{
    const float* nf   = (const float*)d_in[0];
    const float* ef   = (const float*)d_in[1];
    const float* W1   = (const float*)d_in[2];
    const float* b1   = (const float*)d_in[3];
    const float* W2   = (const float*)d_in[4];
    const float* b2   = (const float*)d_in[5];
    const float* wg   = (const float*)d_in[6];
    const float* bg   = (const float*)d_in[7];
    const float* Wh1  = (const float*)d_in[8];
    const float* bh1  = (const float*)d_in[9];
    const float* Wh2  = (const float*)d_in[10];
    const float* bh2  = (const float*)d_in[11];
    const float* Wout = (const float*)d_in[12];
    const float* bout = (const float*)d_in[13];
    const int*   send = (const int*)d_in[14];
    const int*   recv = (const int*)d_in[15];

    // workspace: [cnt|deg|eidb] zeroed, then the rest
    char* ws = (char*)d_ws;
    int* cntp   = (int*)ws;            ws += 16;
    int* deg    = (int*)ws;            ws += (size_t)N_AGENTS * 4;
    int* eidb   = (int*)ws;            ws += (size_t)EPAD * 4;
    size_t zero_bytes = (size_t)(ws - (char*)d_ws);
    int* elist  = (int*)ws;            ws += (size_t)EPAD * 4;
    int* rlist  = (int*)ws;            ws += (size_t)EPAD * 4;
    int* rankl  = (int*)ws;            ws += (size_t)EPAD * 4;
    int* off    = (int*)ws;            ws += (size_t)(N_AGENTS + 8) * 4;
    float* evals = (float*)ws;         ws += (size_t)EPAD * 4;
    f16* F1     = (f16*)ws;            ws += (size_t)160 * 256 * 2;
    f16* F2     = (f16*)ws;            ws += (size_t)256 * 128 * 2;
    f16* F3     = (f16*)ws;            ws += (size_t)128 * 256 * 2;
    f16* F4     = (f16*)ws;            ws += (size_t)256 * 256 * 2;
    f16* msg    = (f16*)ws;

    hipMemsetAsync(d_ws, 0, zero_bytes, stream);

    pack_weights<<<84, 256, 0, stream>>>(W1, W2, Wh1, Wh2, F1, F2, F3, F4);
    compact_kernel<<<N_EDGES / 256, 256, 0, stream>>>(
        recv, elist, rlist, rankl, deg, cntp);
    prefix_kernel<<<1, 1024, 0, stream>>>(deg, off);
    scatter_kernel<<<1024, 256, 0, stream>>>(elist, rlist, rankl, off, cntp, eidb);
    edge_mlp_mfma<<<1024, 512, 0, stream>>>(
        nf, ef, F1, F2, b1, b2, wg, bg, send, recv, eidb, cntp, msg, evals);
    agg_agent_mfma<<<(N_AGENTS + 31) / 32, 1024, 0, stream>>>(
        off, evals, msg, F3, F4, bh1, bh2, Wout, bout, (float*)d_out);
}

// Round 13
// 582.313 us; speedup vs baseline: 1.1564x; 1.0778x over previous
//
#include <hip/hip_runtime.h>
#include <hip/hip_bf16.h>

#define N_NODES  50000
#define N_EDGES  800000
#define ND       64
#define ED       32
#define MSGD     128
#define HIDD     256
#define N_AGENTS 25000
#define EPAD     800064   // N_EDGES + 64 (tile padding)

typedef _Float16 f16;
typedef __attribute__((ext_vector_type(4))) _Float16 f16x4;
typedef __attribute__((ext_vector_type(8))) _Float16 f16x8;
typedef __attribute__((ext_vector_type(4))) float f32x4;
typedef unsigned short u16;
typedef unsigned int   u32;
typedef unsigned long long u64;

// ============================================================================
// pack all four weight matrices into fp16 MFMA A-fragment order.
// frag for 16x16x32: lane l, elem j <-> W[k = ks*32 + (l>>4)*8 + j][n = nt*16 + (l&15)]
// ============================================================================
__global__ __launch_bounds__(256) void pack_weights(
    const float* __restrict__ W1, const float* __restrict__ W2,
    const float* __restrict__ Wh1, const float* __restrict__ Wh2,
    f16* __restrict__ F1, f16* __restrict__ F2,
    f16* __restrict__ F3, f16* __restrict__ F4)
{
    int tid  = blockIdx.x * 256 + threadIdx.x;
    int grp  = tid >> 6, lane = tid & 63;
    const float* W; f16* D; int NT, stride, gl;
    if      (grp < 80)  { W = W1;  D = F1; NT = 16; stride = 256; gl = grp; }
    else if (grp < 144) { W = W2;  D = F2; NT = 8;  stride = 128; gl = grp - 80; }
    else if (grp < 208) { W = Wh1; D = F3; NT = 16; stride = 256; gl = grp - 144; }
    else if (grp < 336) { W = Wh2; D = F4; NT = 16; stride = 256; gl = grp - 208; }
    else return;
    int ks = gl / NT, nt = gl - ks * NT;
    int n  = nt * 16 + (lane & 15);
    int k0 = ks * 32 + (lane >> 4) * 8;
    f16* dst = D + ((size_t)gl * 64 + lane) * 8;
    #pragma unroll
    for (int j = 0; j < 8; ++j)
        dst[j] = (f16)W[(size_t)(k0 + j) * stride + n];
}

// ============================================================================
// compact: keep edges with recv < N_AGENTS; per-receiver rank via atomicAdd.
// ============================================================================
__global__ __launch_bounds__(256) void compact_kernel(
    const int* __restrict__ recv, int* __restrict__ elist,
    int* __restrict__ rlist, int* __restrict__ rankl,
    int* __restrict__ deg, int* __restrict__ cnt)
{
    int i = blockIdx.x * 256 + threadIdx.x;
    int r = recv[i];
    bool keep = (r < N_AGENTS);
    u64 m = __ballot(keep);
    int lane = threadIdx.x & 63;
    int tot = __popcll(m);
    int base = 0;
    if (lane == 0 && tot > 0) base = atomicAdd(cnt, tot);
    base = __shfl(base, 0, 64);
    if (keep) {
        int p = base + __popcll(m & ((1ull << lane) - 1ull));
        int rank = atomicAdd(&deg[r], 1);
        elist[p] = i;
        rlist[p] = r;
        rankl[p] = rank;
    }
}

// ============================================================================
// prefix: exclusive scan deg -> off[25001] (single block)
// ============================================================================
__global__ __launch_bounds__(1024) void prefix_kernel(
    const int* __restrict__ deg, int* __restrict__ off)
{
    __shared__ int part[1024];
    int t = threadIdx.x;
    int i0 = t * 25;
    int s = 0;
    #pragma unroll 1
    for (int i = 0; i < 25; ++i) {
        int idx = i0 + i;
        if (idx < N_AGENTS) s += deg[idx];
    }
    part[t] = s;
    __syncthreads();
    for (int d = 1; d < 1024; d <<= 1) {
        int v = (t >= d) ? part[t - d] : 0;
        __syncthreads();
        part[t] += v;
        __syncthreads();
    }
    int run = (t == 0) ? 0 : part[t - 1];
    #pragma unroll 1
    for (int i = 0; i < 25; ++i) {
        int idx = i0 + i;
        if (idx < N_AGENTS) {
            off[idx] = run;
            run += deg[idx];
        }
    }
    if (t == 1023) off[N_AGENTS] = part[1023];
}

// ============================================================================
// scatter (no atomics): position = off[r] + rank
// ============================================================================
__global__ __launch_bounds__(256) void scatter_kernel(
    const int* __restrict__ elist, const int* __restrict__ rlist,
    const int* __restrict__ rankl, const int* __restrict__ off,
    const int* __restrict__ cnt, int* __restrict__ eidb)
{
    int n = cnt[0];
    for (int ci = blockIdx.x * 256 + threadIdx.x; ci < n; ci += gridDim.x * 256) {
        eidb[off[rlist[ci]] + rankl[ci]] = elist[ci];
    }
}

// ============================================================================
// Edge MLP — R4/R10 core (FETCH ~120 MB), now with XF DOUBLE-BUFFER:
// stage(t+1) issues before layer1(t) with NO barrier between -> waves desync,
// one wave's MFMA covers another's gather stall; 2 barriers/tile (was 3).
// Staging loop body is byte-identical to the R10 idiom (rolled, variable-trip)
// — do NOT restructure it (R8/R9 variants blow FETCH to 450-514 MB).
// Grid 512 (measured optimum; 1024 thrashes L2 — R12). XCD-chunked tiles:
// blockIdx&7 owns a contiguous 1/8 of tiles for per-XCD L2 gather locality.
// ============================================================================
__global__ __launch_bounds__(512, 4) void edge_mlp_mfma(
    const float* __restrict__ nf, const float* __restrict__ ef,
    const f16* __restrict__ F1, const f16* __restrict__ F2,
    const float* __restrict__ b1, const float* __restrict__ b2,
    const float* __restrict__ wg, const float* __restrict__ bg,
    const int* __restrict__ send, const int* __restrict__ recv,
    const int* __restrict__ eidb, const int* __restrict__ cnt,
    f16* __restrict__ msg_out, float* __restrict__ evals)
{
    __shared__ __align__(16) f16 XF[2][10][64][8];  // 20 KB (double buffer)
    __shared__ __align__(16) f16 HB[16][64][8];     // 16 KB
    __shared__ __align__(16) f16 msgt[32][136];     // 8.5 KB
    __shared__ float lpart[8][32];

    const int tid  = threadIdx.x;
    const int wv   = tid >> 6;
    const int lane = tid & 63;
    const int q    = lane >> 4;
    const int li   = lane & 15;
    const int cntv   = cnt[0];
    const int ntiles = (cntv + 31) >> 5;

    // XCD-chunked tile assignment (round-robin blockIdx->XCD heuristic):
    const int xcd   = blockIdx.x & 7;
    const int bslot = blockIdx.x >> 3;
    const int tstep = gridDim.x >> 3;          // blocks per XCD
    const int T8    = (ntiles + 7) >> 3;
    const int tend  = min((xcd + 1) * T8, ntiles);
    const int t0    = xcd * T8 + bslot;

    // stationary weight fragments: W1 2 col-tiles + W2 1 col-tile per wave
    f16x8 w1[2][5], w2[8];
    #pragma unroll
    for (int ntl = 0; ntl < 2; ++ntl)
        #pragma unroll
        for (int ks = 0; ks < 5; ++ks)
            w1[ntl][ks] = *(const f16x8*)(F1 + (((size_t)(ks * 16 + 2 * wv + ntl)) * 64 + lane) * 8);
    #pragma unroll
    for (int ks = 0; ks < 8; ++ks)
        w2[ks] = *(const f16x8*)(F2 + (((size_t)(ks * 8 + wv)) * 64 + lane) * 8);

    const float4 ba  = *(const float4*)&b1[wv * 32 + q * 4];
    const float4 bb  = *(const float4*)&b1[wv * 32 + 16 + q * 4];
    const float4 bc  = *(const float4*)&b2[wv * 16 + q * 4];
    const float4 wg4 = *(const float4*)&wg[wv * 16 + q * 4];
    const float  bgv = bg[0];

    // ---- prologue: stage first tile into XF[0] (R10 idiom) ----
    if (t0 < tend) {
        const int e0p = t0 * 32;
        f16 (*XFd)[64][8] = XF[0];
        for (int idx = tid; idx < 1280; idx += 512) {
            int e = idx / 40, g = idx - e * 40;
            int eid = eidb[e0p + e];
            float4 v;
            if (g < 16)      v = ((const float4*)nf)[(size_t)send[eid] * 16 + g];
            else if (g < 32) v = ((const float4*)nf)[(size_t)recv[eid] * 16 + (g - 16)];
            else             v = ((const float4*)ef)[(size_t)eid * 8 + (g - 32)];
            int k0   = g * 4;
            int slt  = (e >> 4) * 5 + (k0 >> 5);
            int ln   = (e & 15) + 16 * ((k0 & 31) >> 3);
            int j0   = k0 & 7;
            f16x4 h;
            h.x = (f16)v.x; h.y = (f16)v.y; h.z = (f16)v.z; h.w = (f16)v.w;
            *(f16x4*)&XFd[slt][ln][j0] = h;
        }
    }
    __syncthreads();

    int p = 0;
    for (int t = t0; t < tend; t += tstep) {
        const int e0 = t * 32;
        const int tn = t + tstep;

        // ---- stage NEXT tile into XF[p^1] — no barrier before layer1 ----
        if (tn < tend) {
            const int e0n = tn * 32;
            f16 (*XFd)[64][8] = XF[p ^ 1];
            for (int idx = tid; idx < 1280; idx += 512) {
                int e = idx / 40, g = idx - e * 40;
                int eid = eidb[e0n + e];
                float4 v;
                if (g < 16)      v = ((const float4*)nf)[(size_t)send[eid] * 16 + g];
                else if (g < 32) v = ((const float4*)nf)[(size_t)recv[eid] * 16 + (g - 16)];
                else             v = ((const float4*)ef)[(size_t)eid * 8 + (g - 32)];
                int k0   = g * 4;
                int slt  = (e >> 4) * 5 + (k0 >> 5);
                int ln   = (e & 15) + 16 * ((k0 & 31) >> 3);
                int j0   = k0 & 7;
                f16x4 h;
                h.x = (f16)v.x; h.y = (f16)v.y; h.z = (f16)v.z; h.w = (f16)v.w;
                *(f16x4*)&XFd[slt][ln][j0] = h;
            }
        }

        // ---- layer 1: h[col][edge] = W1^T x^T (from XF[p]) ----
        f32x4 acc[2][2];   // [eh][ntl]
        acc[0][0] = f32x4{ba.x, ba.y, ba.z, ba.w}; acc[1][0] = acc[0][0];
        acc[0][1] = f32x4{bb.x, bb.y, bb.z, bb.w}; acc[1][1] = acc[0][1];
        #pragma unroll
        for (int ks = 0; ks < 5; ++ks)
            #pragma unroll
            for (int eh = 0; eh < 2; ++eh) {
                f16x8 xh = *(const f16x8*)XF[p][eh * 5 + ks][lane];
                acc[eh][0] = __builtin_amdgcn_mfma_f32_16x16x32_f16(w1[0][ks], xh, acc[eh][0], 0, 0, 0);
                acc[eh][1] = __builtin_amdgcn_mfma_f32_16x16x32_f16(w1[1][ks], xh, acc[eh][1], 0, 0, 0);
            }
        // relu + stash h as layer-2 B frags
        #pragma unroll
        for (int eh = 0; eh < 2; ++eh)
            #pragma unroll
            for (int ntl = 0; ntl < 2; ++ntl) {
                f16x4 hv;
                hv.x = (f16)fmaxf(acc[eh][ntl][0], 0.f);
                hv.y = (f16)fmaxf(acc[eh][ntl][1], 0.f);
                hv.z = (f16)fmaxf(acc[eh][ntl][2], 0.f);
                hv.w = (f16)fmaxf(acc[eh][ntl][3], 0.f);
                int l2 = li + 16 * (2 * ntl + (q >> 1));
                int j0 = (q & 1) * 4;
                *(f16x4*)&HB[eh * 8 + wv][l2][j0] = hv;
            }
        __syncthreads();   // B1: HB ready; XF[p^1] staged

        // ---- layer 2: msg[col][edge] = W2^T h^T ----
        f32x4 acc2[2];
        acc2[0] = f32x4{bc.x, bc.y, bc.z, bc.w}; acc2[1] = acc2[0];
        #pragma unroll
        for (int ks2 = 0; ks2 < 8; ++ks2)
            #pragma unroll
            for (int eh = 0; eh < 2; ++eh) {
                f16x8 hh = *(const f16x8*)HB[eh * 8 + ks2][lane];
                acc2[eh] = __builtin_amdgcn_mfma_f32_16x16x32_f16(w2[ks2], hh, acc2[eh], 0, 0, 0);
            }
        // relu + gate partial + msg stash
        {
            float pr[2];
            #pragma unroll
            for (int eh = 0; eh < 2; ++eh) {
                float v0 = fmaxf(acc2[eh][0], 0.f);
                float v1 = fmaxf(acc2[eh][1], 0.f);
                float v2 = fmaxf(acc2[eh][2], 0.f);
                float v3 = fmaxf(acc2[eh][3], 0.f);
                f16x4 mm;
                mm.x = (f16)v0; mm.y = (f16)v1; mm.z = (f16)v2; mm.w = (f16)v3;
                *(f16x4*)&msgt[eh * 16 + li][wv * 16 + q * 4] = mm;
                float pp = v0 * wg4.x + v1 * wg4.y + v2 * wg4.z + v3 * wg4.w;
                pp += __shfl_xor(pp, 16, 64);
                pp += __shfl_xor(pp, 32, 64);
                pr[eh] = pp;
            }
            if (lane < 16) {
                lpart[wv][li]      = pr[0];
                lpart[wv][16 + li] = pr[1];
            }
        }
        __syncthreads();   // B2: msgt/lpart ready

        // ---- writeback: coalesced msg rows + evals = exp(logit) ----
        {
            int row = tid >> 4, cg = tid & 15;
            *(uint4*)(msg_out + (size_t)(e0 + row) * 128 + cg * 8) =
                *(const uint4*)&msgt[row][cg * 8];
        }
        if (tid < 32) {
            float s2 = bgv;
            #pragma unroll
            for (int w = 0; w < 8; ++w) s2 += lpart[w][tid];
            evals[e0 + tid] = expf(s2);   // softmax shift-invariant; |logit|~O(5)
        }
        p ^= 1;
    }
}

// ============================================================================
// Fused CSR softmax-aggregation + agent MLP. 1024 thr, 32 receivers/block.
// Aggregation: 32 threads per receiver, 4 cols each (8 B/lane), sequential
// bucket rows (zero atomics, no aggr round-trip). Then fp16-MFMA 2-layer MLP.
// ============================================================================
__global__ __launch_bounds__(1024, 4) void agg_agent_mfma(
    const int* __restrict__ off, const float* __restrict__ evals,
    const f16* __restrict__ msg,
    const f16* __restrict__ F3, const f16* __restrict__ F4,
    const float* __restrict__ bh1, const float* __restrict__ bh2,
    const float* __restrict__ Wout, const float* __restrict__ bout,
    float* __restrict__ out)
{
    __shared__ __align__(16) f16 XA[8][64][8];     // 8 KB
    __shared__ __align__(16) f16 HB2[16][64][8];   // 16 KB
    __shared__ float lpart[16][32];

    const int tid  = threadIdx.x;
    const int wv   = tid >> 6;
    const int lane = tid & 63;
    const int q    = lane >> 4;
    const int li   = lane & 15;
    const int a0i  = blockIdx.x * 32;

    // ---- aggregation straight into XA fragment layout ----
    {
        int g = tid >> 5, c = tid & 31;   // receiver a0i+g, cols [c*4, c*4+4)
        int r = a0i + g;
        float den = 1e-9f;
        float4 acc = make_float4(0.f, 0.f, 0.f, 0.f);
        if (r < N_AGENTS) {
            int beg = off[r], end = off[r + 1];
            const u64* mp = (const u64*)(msg + (size_t)beg * 128) + c;
            for (int p = beg; p < end; ++p, mp += 32) {
                float e = evals[p];
                den += e;
                union { u64 u; f16 h[4]; } cv; cv.u = *mp;
                acc.x = fmaf(e, (float)cv.h[0], acc.x);
                acc.y = fmaf(e, (float)cv.h[1], acc.y);
                acc.z = fmaf(e, (float)cv.h[2], acc.z);
                acc.w = fmaf(e, (float)cv.h[3], acc.w);
            }
        }
        float inv = 1.0f / den;
        int k0   = c * 4;
        int slot = (g >> 4) * 4 + (k0 >> 5);
        int ln   = (g & 15) + 16 * ((k0 & 31) >> 3);
        int j0   = k0 & 7;
        f16x4 h;
        h.x = (f16)(acc.x * inv); h.y = (f16)(acc.y * inv);
        h.z = (f16)(acc.z * inv); h.w = (f16)(acc.w * inv);
        *(f16x4*)&XA[slot][ln][j0] = h;
    }
    __syncthreads();

    // ---- weight fragments + layer 1 ----
    f16x8 wh1[4], wh2[8];
    #pragma unroll
    for (int ks = 0; ks < 4; ++ks)
        wh1[ks] = *(const f16x8*)(F3 + (((size_t)(ks * 16 + wv)) * 64 + lane) * 8);
    #pragma unroll
    for (int ks = 0; ks < 8; ++ks)
        wh2[ks] = *(const f16x8*)(F4 + (((size_t)(ks * 16 + wv)) * 64 + lane) * 8);

    f32x4 acc[2] = {};
    #pragma unroll
    for (int ks = 0; ks < 4; ++ks)
        #pragma unroll
        for (int eh = 0; eh < 2; ++eh) {
            f16x8 xh = *(const f16x8*)XA[eh * 4 + ks][lane];
            acc[eh] = __builtin_amdgcn_mfma_f32_16x16x32_f16(wh1[ks], xh, acc[eh], 0, 0, 0);
        }
    {
        const float4 b1v = ((const float4*)bh1)[wv * 4 + q];
        #pragma unroll
        for (int eh = 0; eh < 2; ++eh) {
            f16x4 hv;
            hv.x = (f16)fmaxf(acc[eh][0] + b1v.x, 0.f);
            hv.y = (f16)fmaxf(acc[eh][1] + b1v.y, 0.f);
            hv.z = (f16)fmaxf(acc[eh][2] + b1v.z, 0.f);
            hv.w = (f16)fmaxf(acc[eh][3] + b1v.w, 0.f);
            int l2 = li + 16 * ((wv & 1) * 2 + (q >> 1));
            int j0 = (q & 1) * 4;
            *(f16x4*)&HB2[eh * 8 + (wv >> 1)][l2][j0] = hv;
        }
    }
    __syncthreads();

    // ---- layer 2 + output partial ----
    f32x4 acc2[2] = {};
    #pragma unroll
    for (int ks2 = 0; ks2 < 8; ++ks2)
        #pragma unroll
        for (int eh = 0; eh < 2; ++eh) {
            f16x8 hh = *(const f16x8*)HB2[eh * 8 + ks2][lane];
            acc2[eh] = __builtin_amdgcn_mfma_f32_16x16x32_f16(wh2[ks2], hh, acc2[eh], 0, 0, 0);
        }
    {
        const float4 b2v = ((const float4*)bh2)[wv * 4 + q];
        const float4 wo4 = ((const float4*)Wout)[wv * 4 + q];
        float pr[2];
        #pragma unroll
        for (int eh = 0; eh < 2; ++eh) {
            float pp = fmaxf(acc2[eh][0] + b2v.x, 0.f) * wo4.x
                     + fmaxf(acc2[eh][1] + b2v.y, 0.f) * wo4.y
                     + fmaxf(acc2[eh][2] + b2v.z, 0.f) * wo4.z
                     + fmaxf(acc2[eh][3] + b2v.w, 0.f) * wo4.w;
            pp += __shfl_xor(pp, 16, 64);
            pp += __shfl_xor(pp, 32, 64);
            pr[eh] = pp;
        }
        if (lane < 16) {
            lpart[wv][li]      = pr[0];
            lpart[wv][16 + li] = pr[1];
        }
    }
    __syncthreads();

    if (tid < 32 && a0i + tid < N_AGENTS) {
        float s = bout[0];
        #pragma unroll
        for (int w = 0; w < 16; ++w) s += lpart[w][tid];
        out[a0i + tid] = tanhf(s);
    }
}

// ============================================================================
extern "C" void kernel_launch(void* const* d_in, const int* in_sizes, int n_in,
                              void* d_out, int out_size, void* d_ws, size_t ws_size,
                              hipStream_t stream)
{
    const float* nf   = (const float*)d_in[0];
    const float* ef   = (const float*)d_in[1];
    const float* W1   = (const float*)d_in[2];
    const float* b1   = (const float*)d_in[3];
    const float* W2   = (const float*)d_in[4];
    const float* b2   = (const float*)d_in[5];
    const float* wg   = (const float*)d_in[6];
    const float* bg   = (const float*)d_in[7];
    const float* Wh1  = (const float*)d_in[8];
    const float* bh1  = (const float*)d_in[9];
    const float* Wh2  = (const float*)d_in[10];
    const float* bh2  = (const float*)d_in[11];
    const float* Wout = (const float*)d_in[12];
    const float* bout = (const float*)d_in[13];
    const int*   send = (const int*)d_in[14];
    const int*   recv = (const int*)d_in[15];

    // workspace: [cnt|deg|eidb] zeroed, then the rest
    char* ws = (char*)d_ws;
    int* cntp   = (int*)ws;            ws += 16;
    int* deg    = (int*)ws;            ws += (size_t)N_AGENTS * 4;
    int* eidb   = (int*)ws;            ws += (size_t)EPAD * 4;
    size_t zero_bytes = (size_t)(ws - (char*)d_ws);
    int* elist  = (int*)ws;            ws += (size_t)EPAD * 4;
    int* rlist  = (int*)ws;            ws += (size_t)EPAD * 4;
    int* rankl  = (int*)ws;            ws += (size_t)EPAD * 4;
    int* off    = (int*)ws;            ws += (size_t)(N_AGENTS + 8) * 4;
    float* evals = (float*)ws;         ws += (size_t)EPAD * 4;
    f16* F1     = (f16*)ws;            ws += (size_t)160 * 256 * 2;
    f16* F2     = (f16*)ws;            ws += (size_t)256 * 128 * 2;
    f16* F3     = (f16*)ws;            ws += (size_t)128 * 256 * 2;
    f16* F4     = (f16*)ws;            ws += (size_t)256 * 256 * 2;
    f16* msg    = (f16*)ws;

    hipMemsetAsync(d_ws, 0, zero_bytes, stream);

    pack_weights<<<84, 256, 0, stream>>>(W1, W2, Wh1, Wh2, F1, F2, F3, F4);
    compact_kernel<<<N_EDGES / 256, 256, 0, stream>>>(
        recv, elist, rlist, rankl, deg, cntp);
    prefix_kernel<<<1, 1024, 0, stream>>>(deg, off);
    scatter_kernel<<<1024, 256, 0, stream>>>(elist, rlist, rankl, off, cntp, eidb);
    edge_mlp_mfma<<<512, 512, 0, stream>>>(
        nf, ef, F1, F2, b1, b2, wg, bg, send, recv, eidb, cntp, msg, evals);
    agg_agent_mfma<<<(N_AGENTS + 31) / 32, 1024, 0, stream>>>(
        off, evals, msg, F3, F4, bh1, bh2, Wout, bout, (float*)d_out);
}